// Round 1
// 75.220 us; speedup vs baseline: 1.0964x; 1.0964x over previous
//
#include <hip/hip_runtime.h>

// ---------------------------------------------------------------------------
// KAN conv, fully fused (round 6):
//   out[b,o,oh,ow] = sum_{di,dj,j,c} feat_j(x[b,c,oh+di-1,ow+dj-1]) * Wb[o,pos,j,c] + bias[o]
//   feat_0 = silu(t), feat_1..8 = cubic B-spline bases (t=0 outside image)
//
// Round-6 changes vs round-5 (theory: Phase A = largest removable cost):
//  * ohalf merge: grid 256 = (b 8) x (oh 32), 1024 thr = 16 waves (og x4, kq x4).
//    Halves ALL Phase A work chip-wide; Wb/L2 + DS-read totals unchanged.
//  * sparse basis store: pre-zero feat (b128), write only the 4 nonzero
//    B-spline weights (cndmask'd LDS addr -> dump line for out-of-range jj).
//    ~140 -> ~57 VALU/cell, values bit-identical to dense writes.
//  * kan_prep rewritten: block-per-o LDS transpose, coalesced coef loads and
//    coalesced Wb stores (was 36B/288B-strided gathers).
// Workspace use: Wb only (331,776 B). Poison fill (~40us, 256MiB) is harness
// overhead outside our control; kernel-side target is prep+fused.
// ---------------------------------------------------------------------------

typedef __attribute__((ext_vector_type(8))) short v8s;
typedef __attribute__((ext_vector_type(4))) float v4f;
typedef __attribute__((ext_vector_type(4))) int   v4i;
typedef unsigned short ushort_t;

#define CELL_STRIDE 296                  // ushort elems/cell = 592 B (16B-aligned, bank-friendly)
#define ROW_STRIDE  (34 * CELL_STRIDE)   // 10,064 elems = 20,128 B

__device__ __forceinline__ unsigned short f2bf(float v) {
  union { float f; unsigned int u; } w; w.f = v;
  unsigned int r = w.u + 0x7FFFu + ((w.u >> 16) & 1u);   // RNE
  return (unsigned short)(r >> 16);
}

// ---------------------------------------------------------------------------
// Kernel 1: fold weights  Wb[o][pos][j][c] = (j==0 ? sb : ssp*coef[j-1]), bf16
// One block per o. coef loads linear (coalesced), LDS transpose, Wb stores
// linear (coalesced u32 pairs).
// ---------------------------------------------------------------------------
__global__ __launch_bounds__(256) void kan_prep(const float* __restrict__ coef,
                                                const float* __restrict__ sb,
                                                const float* __restrict__ ssp,
                                                ushort_t* __restrict__ Wb) {
  __shared__ ushort_t row_[2592];
  const int o   = blockIdx.x;
  const int tid = threadIdx.x;
  const float* cf   = coef + o * 2304;   // [c][pos][m] = 32*9*8
  const float* sspo = ssp  + o * 288;    // [c][pos]
  const float* sbo  = sb   + o * 288;

#pragma unroll
  for (int k = 0; k < 9; ++k) {
    int l   = k * 256 + tid;             // 0..2303, linear in coef
    int c   = l / 72;
    int rem = l - c * 72;
    int pos = rem >> 3;
    int m   = rem & 7;
    float v = sspo[c * 9 + pos] * cf[l];
    row_[(pos * 9 + m + 1) * 32 + c] = f2bf(v);     // [pos][j=m+1][c]
  }
  for (int t = tid; t < 288; t += 256) {            // j = 0 plane
    int c = t / 9, pos = t - c * 9;
    row_[(pos * 9) * 32 + c] = f2bf(sbo[t]);
  }
  __syncthreads();
  unsigned int* dst = (unsigned int*)(Wb + (size_t)o * 2592);
  const unsigned int* src = (const unsigned int*)row_;
  for (int i = tid; i < 1296; i += 256) dst[i] = src[i];
}

// ---------------------------------------------------------------------------
// K-loop over flat step s = di*27 + dj*9 + kk; all offsets compile-time.
// (unchanged from round 5 — verified MFMA path)
// ---------------------------------------------------------------------------
template <int LO, int HI>
__device__ __forceinline__ void kloop(const ushort_t* __restrict__ fb,
                                      const ushort_t* __restrict__ wp,
                                      v4f& acc0, v4f& acc1) {
#pragma unroll
  for (int s = LO; s < HI; ++s) {
    const int di = s / 27;
    const int dj = (s / 9) % 3;
    const int kk = s % 9;
    const int fo = di * ROW_STRIDE + dj * CELL_STRIDE + kk * 32;
    v8s wf = *(const v8s*)(wp + s * 32);
    v8s a0 = *(const v8s*)(fb + fo);
    v8s a1 = *(const v8s*)(fb + fo + 16 * CELL_STRIDE);
    acc0 = __builtin_amdgcn_mfma_f32_16x16x32_bf16(wf, a0, acc0, 0, 0, 0);
    acc1 = __builtin_amdgcn_mfma_f32_16x16x32_bf16(wf, a1, acc1, 0, 0, 0);
  }
}

// ---------------------------------------------------------------------------
// Kernel 2: fused feat + conv + reduce.
// grid 256 = (b 8) x (oh 32); 1024 thr = 16 waves = (kq 4) x (og 4).
// ---------------------------------------------------------------------------
__global__ __launch_bounds__(1024, 4) void kan_fused(const float* __restrict__ x,
                                                     const ushort_t* __restrict__ Wb,
                                                     const float* __restrict__ bias,
                                                     float* __restrict__ out) {
  __shared__ __align__(16) ushort_t feat[3 * ROW_STRIDE];  // 60,384 B
  __shared__ float xs[32 * 33];                            // 4,224 B
  __shared__ ushort_t dump[64];                            // sink for invalid jj

  const int tid = threadIdx.x;
  const int bx  = blockIdx.x;                // b*32 + oh
  const int oh  = bx & 31;
  const int b   = bx >> 5;

  // ---- pre-zero feat (b128 stores; barrier below covers the hazard) ----
  {
    v4i z = {0, 0, 0, 0};
    v4i* fz = (v4i*)feat;                    // 3,774 x 16B
#pragma unroll
    for (int k = 0; k < 4; ++k) {
      int i = tid + k * 1024;
      if (i < 3774) fz[i] = z;
    }
  }

  // ---- Phase A: feature strip for padded rows r=0..2 (input h = oh+r-1) ----
  for (int r = 0; r < 3; ++r) {
    const int h = oh + r - 1;
    const bool hval = (h >= 0) && (h < 32);
    if (hval) {
      int c = tid >> 5, w = tid & 31;        // 1024 floats: 32c x 32w
      xs[c * 33 + w] = x[(((b * 32 + c) * 32 + h) * 32 + w)];
    }
    __syncthreads();
    for (int idx = tid; idx < 1088; idx += 1024) {  // 34 cells x 32 c
      int c = idx & 31, cell = idx >> 5;
      int wi = cell - 1;
      float t = 0.0f;
      if (hval && wi >= 0 && wi < 32) t = xs[c * 33 + wi];

      unsigned short f0 = f2bf(t / (1.0f + __expf(-t)));   // silu
      float u  = (t + 2.2f) * 2.5f;                        // spline param
      float fi = floorf(u);
      int   i  = (int)fi;
      float s  = u - fi;
      float s2 = s * s, s3 = s2 * s;
      float om = 1.0f - s;
      float w0 = om * om * om * (1.0f / 6.0f);
      float w1 = (4.0f - 6.0f * s2 + 3.0f * s3) * (1.0f / 6.0f);
      float w2 = (1.0f + 3.0f * s + 3.0f * s2 - 3.0f * s3) * (1.0f / 6.0f);
      float w3 = s3 * (1.0f / 6.0f);

      ushort_t* cb = feat + r * ROW_STRIDE + cell * CELL_STRIDE + c;
      cb[0] = f0;
      // only 4 bases are nonzero: basis jj = i-3+d gets w_d, d=0..3
#pragma unroll
      for (int d = 0; d < 4; ++d) {
        float wv_ = (d == 0) ? w0 : (d == 1) ? w1 : (d == 2) ? w2 : w3;
        int jj = i - 3 + d;
        ushort_t* p = ((unsigned)jj <= 7u) ? (cb + (jj + 1) * 32)
                                           : (dump + (tid & 63));
        *p = f2bf(wv_);
      }
    }
    __syncthreads();
  }

  // ---- Phase B: MFMA.  wave = (og: O16-group x4) x M32, kq = K-quarter ----
  const int wv   = tid >> 6;
  const int lane = tid & 63;
  const int row  = lane & 15;
  const int quad = lane >> 4;
  const int og   = wv & 3;
  const int kq   = wv >> 2;
  const int obase = og * 16;

  const ushort_t* fb = feat + row * CELL_STRIDE + quad * 8;
  const ushort_t* wp = Wb + (size_t)(obase + row) * 2592 + quad * 8;

  v4f acc0 = {0.f, 0.f, 0.f, 0.f};
  v4f acc1 = acc0;

  if (kq == 0)      kloop<0, 20>(fb, wp, acc0, acc1);
  else if (kq == 1) kloop<20, 40>(fb, wp, acc0, acc1);
  else if (kq == 2) kloop<40, 60>(fb, wp, acc0, acc1);
  else              kloop<60, 81>(fb, wp, acc0, acc1);

  // ---- Phase C: cross-wave reduce via dead feat LDS, + bias, store ----
  __syncthreads();
  float* red = (float*)feat;                 // 12 groups x 512 fp32 = 24 KB
  if (kq != 0) {
    float* rp = red + ((kq - 1) * 4 + og) * 512 + quad * 4 * 32 + row;
#pragma unroll
    for (int r = 0; r < 4; ++r) {
      rp[r * 32]      = acc0[r];             // pix = row      (m=0)
      rp[r * 32 + 16] = acc1[r];             // pix = 16 + row (m=1)
    }
  }
  __syncthreads();
  if (kq == 0) {
    float* o0 = out + ((size_t)(b * 64 + obase + quad * 4)) * 1024 + oh * 32 + row;
#pragma unroll
    for (int r = 0; r < 4; ++r) {
      float bv = bias[obase + quad * 4 + r];
      float s0 = acc0[r], s1 = acc1[r];
#pragma unroll
      for (int gs = 0; gs < 3; ++gs) {
        const float* rp = red + (gs * 4 + og) * 512 + (quad * 4 + r) * 32 + row;
        s0 += rp[0];
        s1 += rp[16];
      }
      o0[(size_t)r * 1024]      = s0 + bv;
      o0[(size_t)r * 1024 + 16] = s1 + bv;
    }
  }
}

// ---------------------------------------------------------------------------
extern "C" void kernel_launch(void* const* d_in, const int* in_sizes, int n_in,
                              void* d_out, int out_size, void* d_ws, size_t ws_size,
                              hipStream_t stream) {
  const float* x    = (const float*)d_in[0];
  const float* coef = (const float*)d_in[1];
  const float* sb   = (const float*)d_in[2];
  const float* ssp  = (const float*)d_in[3];
  const float* bias = (const float*)d_in[4];
  float* out = (float*)d_out;

  ushort_t* Wb = (ushort_t*)d_ws;            // 331,776 B

  hipLaunchKernelGGL(kan_prep, dim3(64), dim3(256), 0, stream, coef, sb, ssp, Wb);
  hipLaunchKernelGGL(kan_fused, dim3(256), dim3(1024), 0, stream, x, Wb, bias, out);
}